// Round 1
// baseline (485.603 us; speedup 1.0000x reference)
//
#include <hip/hip_runtime.h>
#include <hip/hip_bf16.h>
#include <cstdint>
#include <cstddef>

#define HIDDEN 1024
#define BATCH 16
#define SEQ 2048
#define M_TOTAL (BATCH*SEQ)
#define NEG_INF -1000000000.0f

typedef unsigned short u16;
typedef __bf16 bf16x8 __attribute__((ext_vector_type(8)));
typedef unsigned short u16x8 __attribute__((ext_vector_type(8)));
typedef unsigned short u16x4 __attribute__((ext_vector_type(4)));
typedef float f32x4 __attribute__((ext_vector_type(4)));

__device__ __forceinline__ u16 f2bf(float f) {
    // round-to-nearest-even fp32 -> bf16 (inputs are finite)
    unsigned int x = __float_as_uint(f);
    unsigned int r = (x + 0x7fffu + ((x >> 16) & 1u)) >> 16;
    return (u16)r;
}

__device__ __forceinline__ float fast_tanh(float x) {
    // tanh(x) = 1 - 2/(e^{2x}+1); safe at +/-inf of the exp
    float e = __expf(2.0f * x);
    return 1.0f - 2.0f / (e + 1.0f);
}

// ---------------------------------------------------------------------------
// Kernel 1: q_proj[b,n] = sum_k query[b,k] * W1[k,n]   (fp32)
// grid (16 n-tiles of 64, 16 b), 256 thr: 4 k-chunks x 64 n per block
// ---------------------------------------------------------------------------
__global__ __launch_bounds__(256) void qproj_kernel(
    const float* __restrict__ q, const float* __restrict__ W1,
    float* __restrict__ qp)
{
    const int b  = blockIdx.y;
    const int tl = threadIdx.x & 63;
    const int kc = threadIdx.x >> 6;        // 0..3
    const int n  = blockIdx.x * 64 + tl;
    __shared__ float red[4][64];

    const float* qrow = q + b * HIDDEN;
    float acc = 0.f;
    #pragma unroll 8
    for (int k = kc * 256; k < kc * 256 + 256; ++k)
        acc += qrow[k] * W1[(size_t)k * HIDDEN + n];
    red[kc][tl] = acc;
    __syncthreads();
    if (kc == 0)
        qp[b * HIDDEN + n] = red[0][tl] + red[1][tl] + red[2][tl] + red[3][tl];
}

// ---------------------------------------------------------------------------
// Kernel 2: W2T[n][k] = bf16(W2[k][n])   -- 64x64 LDS transpose tiles
// grid (16 n-tiles, 16 k-tiles), 256 thr
// ---------------------------------------------------------------------------
__global__ __launch_bounds__(256) void w2t_kernel(
    const float* __restrict__ W2, u16* __restrict__ W2T)
{
    __shared__ float tile[64][65];
    const int n0 = blockIdx.x * 64, k0 = blockIdx.y * 64;
    const int tid = threadIdx.x;
    const int c = tid & 63, rb = tid >> 6;
    #pragma unroll
    for (int i = 0; i < 16; ++i) {
        int r = rb + i * 4;
        tile[r][c] = W2[(size_t)(k0 + r) * HIDDEN + n0 + c];
    }
    __syncthreads();
    #pragma unroll
    for (int i = 0; i < 16; ++i) {
        int r = rb + i * 4;
        W2T[(size_t)(n0 + r) * HIDDEN + k0 + c] = f2bf(tile[c][r]);
    }
}

// ---------------------------------------------------------------------------
// Kernel 3: fused scores GEMM.
// part[slot][m] = sum_{n in 64-col slice} tanh(keys@W2 + qp)[m,n] * v[n]
// slot = ntile*2 + wave_col, 16 slots total. 128x128 tile, BK=64,
// mfma_f32_16x16x32_bf16, 4 waves in 2x2, 4x4 16x16 tiles per wave.
// ---------------------------------------------------------------------------
#define BM 128
#define BN 128
#define BK 64
#define LDA 72   // BK + 8 pad (stride 144 B: 16B-aligned, 2-way-max banks)

__global__ __launch_bounds__(256) void scores_kernel(
    const float* __restrict__ keys,
    const u16*   __restrict__ W2T,
    const float* __restrict__ qp,
    const float* __restrict__ v,
    float*       __restrict__ part)
{
    __shared__ __align__(16) u16 Alds[BM][LDA];
    __shared__ __align__(16) u16 Blds[BN][LDA];

    const int tid  = threadIdx.x;
    const int m0   = blockIdx.x * BM;       // 256 m-tiles
    const int nt   = blockIdx.y;            // 8 n-tiles
    const int n0   = nt * BN;
    const int wave = tid >> 6, lane = tid & 63;
    const int wr = wave >> 1, wc = wave & 1;
    const int quad = lane >> 4, c16 = lane & 15;

    f32x4 acc[4][4];
    #pragma unroll
    for (int i = 0; i < 4; ++i)
        #pragma unroll
        for (int j = 0; j < 4; ++j)
            acc[i][j] = f32x4{0.f, 0.f, 0.f, 0.f};

    for (int kt = 0; kt < HIDDEN; kt += BK) {
        __syncthreads();
        // stage A: 128x64 fp32 -> bf16, 2048 float4, 8 per thread
        const float* gA = keys + (size_t)m0 * HIDDEN + kt;
        #pragma unroll
        for (int i = 0; i < 8; ++i) {
            int idx = tid + i * 256;
            int r = idx >> 4, c4 = idx & 15;
            float4 f = *(const float4*)(gA + (size_t)r * HIDDEN + c4 * 4);
            u16x4 pk;
            pk[0] = f2bf(f.x); pk[1] = f2bf(f.y);
            pk[2] = f2bf(f.z); pk[3] = f2bf(f.w);
            *(u16x4*)&Alds[r][c4 * 4] = pk;
        }
        // stage B: 128x64 bf16 copy, 1024 x 16B, 4 per thread
        #pragma unroll
        for (int i = 0; i < 4; ++i) {
            int idx = tid + i * 256;
            int r = idx >> 3, c8 = idx & 7;
            uint4 raw = ((const uint4*)(W2T + (size_t)(n0 + r) * HIDDEN + kt))[c8];
            *(uint4*)&Blds[r][c8 * 8] = raw;
        }
        __syncthreads();

        #pragma unroll
        for (int ks = 0; ks < BK; ks += 32) {
            bf16x8 af[4], bfr[4];
            #pragma unroll
            for (int i = 0; i < 4; ++i)
                af[i] = __builtin_bit_cast(bf16x8,
                    *(const u16x8*)&Alds[wr * 64 + i * 16 + c16][ks + quad * 8]);
            #pragma unroll
            for (int j = 0; j < 4; ++j)
                bfr[j] = __builtin_bit_cast(bf16x8,
                    *(const u16x8*)&Blds[wc * 64 + j * 16 + c16][ks + quad * 8]);
            #pragma unroll
            for (int i = 0; i < 4; ++i)
                #pragma unroll
                for (int j = 0; j < 4; ++j)
                    acc[i][j] = __builtin_amdgcn_mfma_f32_16x16x32_bf16(
                        af[i], bfr[j], acc[i][j], 0, 0, 0);
        }
    }

    // epilogue: tanh(acc + qp[b,n]) * v[n], reduce over this wave's 64 cols
    const int b = m0 >> 11;                 // m0 / SEQ (tile within one batch)
    float qv[4], vv[4];
    #pragma unroll
    for (int j = 0; j < 4; ++j) {
        int n = n0 + wc * 64 + j * 16 + c16;
        qv[j] = qp[b * HIDDEN + n];
        vv[j] = v[n];
    }
    const int slot = nt * 2 + wc;
    #pragma unroll
    for (int i = 0; i < 4; ++i) {
        #pragma unroll
        for (int r = 0; r < 4; ++r) {
            float s = 0.f;
            #pragma unroll
            for (int j = 0; j < 4; ++j)
                s += fast_tanh(acc[i][j][r] + qv[j]) * vv[j];
            // sum across the 16 lanes of this quad (cols of the 16x16 tile)
            s += __shfl_xor(s, 1);
            s += __shfl_xor(s, 2);
            s += __shfl_xor(s, 4);
            s += __shfl_xor(s, 8);
            if (c16 == 0) {
                int m = m0 + wr * 64 + i * 16 + quad * 4 + r;
                part[(size_t)slot * M_TOTAL + m] = s;
            }
        }
    }
}

// ---------------------------------------------------------------------------
// Kernel 4: scores = sum(part) -> mask -> softmax over s -> attn weights
// grid 16 (one block per batch), 256 thr x 8 s each
// ---------------------------------------------------------------------------
__global__ __launch_bounds__(256) void softmax_kernel(
    const float* __restrict__ part, const int* __restrict__ mask,
    float* __restrict__ attn)
{
    const int b = blockIdx.x, tid = threadIdx.x;
    const int wave = tid >> 6, lane = tid & 63;
    __shared__ float red[4];
    float sc[8];
    float mx = -1e30f;
    #pragma unroll
    for (int j = 0; j < 8; ++j) {
        int s = tid + j * 256;
        float a = 0.f;
        #pragma unroll
        for (int p = 0; p < 16; ++p)
            a += part[(size_t)p * M_TOTAL + b * SEQ + s];
        if (mask[b * SEQ + s] == 0) a = NEG_INF;
        sc[j] = a;
        mx = fmaxf(mx, a);
    }
    #pragma unroll
    for (int o = 32; o > 0; o >>= 1) mx = fmaxf(mx, __shfl_xor(mx, o));
    if (lane == 0) red[wave] = mx;
    __syncthreads();
    mx = fmaxf(fmaxf(red[0], red[1]), fmaxf(red[2], red[3]));
    float sum = 0.f;
    #pragma unroll
    for (int j = 0; j < 8; ++j) { sc[j] = __expf(sc[j] - mx); sum += sc[j]; }
    #pragma unroll
    for (int o = 32; o > 0; o >>= 1) sum += __shfl_xor(sum, o);
    __syncthreads();
    if (lane == 0) red[wave] = sum;
    __syncthreads();
    sum = red[0] + red[1] + red[2] + red[3];
    float inv = 1.0f / sum;
    #pragma unroll
    for (int j = 0; j < 8; ++j)
        attn[b * SEQ + tid + j * 256] = sc[j] * inv;
}

// ---------------------------------------------------------------------------
// Kernel 5: context[b,h] += sum_s attn[b,s] * values[b,s,h]
// grid (16 b, 16 s-chunks of 128), 256 thr x float4 over h; skip w==0
// ---------------------------------------------------------------------------
__global__ __launch_bounds__(256) void context_kernel(
    const float* __restrict__ values, const float* __restrict__ attn,
    float* __restrict__ ctx)
{
    const int b = blockIdx.x, sch = blockIdx.y, tid = threadIdx.x;
    __shared__ float w[128];
    if (tid < 128) w[tid] = attn[b * SEQ + sch * 128 + tid];
    __syncthreads();
    float4 acc = {0.f, 0.f, 0.f, 0.f};
    const float4* V = (const float4*)(values
        + (size_t)b * SEQ * HIDDEN + (size_t)sch * 128 * HIDDEN);
    for (int s = 0; s < 128; ++s) {
        float wv = w[s];               // block-uniform -> scalar branch
        if (wv != 0.0f) {
            float4 x = V[(size_t)s * (HIDDEN / 4) + tid];
            acc.x += wv * x.x; acc.y += wv * x.y;
            acc.z += wv * x.z; acc.w += wv * x.w;
        }
    }
    float* out = ctx + b * HIDDEN + tid * 4;
    atomicAdd(out + 0, acc.x);
    atomicAdd(out + 1, acc.y);
    atomicAdd(out + 2, acc.z);
    atomicAdd(out + 3, acc.w);
}

// ---------------------------------------------------------------------------
extern "C" void kernel_launch(void* const* d_in, const int* in_sizes, int n_in,
                              void* d_out, int out_size, void* d_ws, size_t ws_size,
                              hipStream_t stream)
{
    const float* query  = (const float*)d_in[0];
    const float* keys   = (const float*)d_in[1];
    const float* values = (const float*)d_in[2];
    const int*   mask   = (const int*)d_in[3];
    const float* W1     = (const float*)d_in[4];
    const float* W2     = (const float*)d_in[5];
    const float* v      = (const float*)d_in[6];
    float* out = (float*)d_out;

    // ws layout: qp (64 KiB) | W2T bf16 (2 MiB) | part (16 x 32768 f32, 2 MiB)
    char* ws = (char*)d_ws;
    float* qp   = (float*)ws;
    u16*   w2t  = (u16*)(ws + 65536);
    float* part = (float*)(ws + 65536 + 2 * 1024 * 1024);

    float* attn_out = out + BATCH * HIDDEN;   // second output chunk
    // zero the context region (we accumulate with atomics)
    hipMemsetAsync(d_out, 0, BATCH * HIDDEN * sizeof(float), stream);

    qproj_kernel<<<dim3(16, 16), 256, 0, stream>>>(query, W1, qp);
    w2t_kernel  <<<dim3(16, 16), 256, 0, stream>>>(W2, w2t);
    scores_kernel<<<dim3(M_TOTAL / BM, HIDDEN / BN), 256, 0, stream>>>(
        keys, w2t, qp, v, part);
    softmax_kernel<<<16, 256, 0, stream>>>(part, mask, attn_out);
    context_kernel<<<dim3(16, 16), 256, 0, stream>>>(values, attn_out, out);
}

// Round 3
// 413.632 us; speedup vs baseline: 1.1740x; 1.1740x over previous
//
#include <hip/hip_runtime.h>
#include <hip/hip_bf16.h>
#include <cstdint>
#include <cstddef>

#define HIDDEN 1024
#define BATCH 16
#define SEQ 2048
#define M_TOTAL (BATCH*SEQ)
#define NEG_INF -1000000000.0f

typedef unsigned short u16;
typedef __bf16 bf16x8 __attribute__((ext_vector_type(8)));
typedef unsigned short u16x8 __attribute__((ext_vector_type(8)));
typedef unsigned short u16x4 __attribute__((ext_vector_type(4)));
typedef float f32x4 __attribute__((ext_vector_type(4)));

typedef const __attribute__((address_space(1))) void* gas_ptr;
typedef __attribute__((address_space(3))) void* las_ptr;

__device__ __forceinline__ u16 f2bf(float f) {
    unsigned int x = __float_as_uint(f);
    unsigned int r = (x + 0x7fffu + ((x >> 16) & 1u)) >> 16;
    return (u16)r;
}

__device__ __forceinline__ float fast_tanh(float x) {
    float e = __expf(2.0f * x);
    return 1.0f - 2.0f / (e + 1.0f);
}

// ---------------------------------------------------------------------------
// q_proj[b,n] = sum_k query[b,k] * W1[k,n]   (fp32)
// ---------------------------------------------------------------------------
__global__ __launch_bounds__(256) void qproj_kernel(
    const float* __restrict__ q, const float* __restrict__ W1,
    float* __restrict__ qp)
{
    const int b  = blockIdx.y;
    const int tl = threadIdx.x & 63;
    const int kc = threadIdx.x >> 6;
    const int n  = blockIdx.x * 64 + tl;
    __shared__ float red[4][64];

    const float* qrow = q + b * HIDDEN;
    float acc = 0.f;
    #pragma unroll 8
    for (int k = kc * 256; k < kc * 256 + 256; ++k)
        acc += qrow[k] * W1[(size_t)k * HIDDEN + n];
    red[kc][tl] = acc;
    __syncthreads();
    if (kc == 0)
        qp[b * HIDDEN + n] = red[0][tl] + red[1][tl] + red[2][tl] + red[3][tl];
}

// ---------------------------------------------------------------------------
// W2T[n][k] = bf16(W2[k][n])
// ---------------------------------------------------------------------------
__global__ __launch_bounds__(256) void w2t_kernel(
    const float* __restrict__ W2, u16* __restrict__ W2T)
{
    __shared__ float tile[64][65];
    const int n0 = blockIdx.x * 64, k0 = blockIdx.y * 64;
    const int tid = threadIdx.x;
    const int c = tid & 63, rb = tid >> 6;
    #pragma unroll
    for (int i = 0; i < 16; ++i) {
        int r = rb + i * 4;
        tile[r][c] = W2[(size_t)(k0 + r) * HIDDEN + n0 + c];
    }
    __syncthreads();
    #pragma unroll
    for (int i = 0; i < 16; ++i) {
        int r = rb + i * 4;
        W2T[(size_t)(n0 + r) * HIDDEN + k0 + c] = f2bf(tile[c][r]);
    }
}

// ---------------------------------------------------------------------------
// keys (fp32, row-major) -> keys_bf (bf16, row-major).
// M_TOTAL*HIDDEN/4 = 8388608 float4 -> 32768 blocks x 256 thr x 1 float4.
// ---------------------------------------------------------------------------
__global__ __launch_bounds__(256) void conv_kernel(
    const float* __restrict__ in, u16* __restrict__ out)
{
    int i = blockIdx.x * 256 + threadIdx.x;     // float4 index, 8M total
    float4 f = ((const float4*)in)[i];
    u16x4 p;
    p[0] = f2bf(f.x); p[1] = f2bf(f.y); p[2] = f2bf(f.z); p[3] = f2bf(f.w);
    ((u16x4*)out)[i] = p;
}

// ---------------------------------------------------------------------------
// scores v2: bf16 A (pre-converted) and B via global_load_lds(16B) with
// XOR-swizzled LDS ([row][chunk^(row&7)], chunk = 16B unit). 128x128 tile,
// BK=64, mfma 16x16x32. grid (nt=8 fastest for keys L2 reuse, 256 m-tiles).
// Epilogue: part[slot][m] = sum_{64-col slice} tanh(acc+qp)*v
// ---------------------------------------------------------------------------
#define BM 128
#define BN 128
#define BK 64

__global__ __launch_bounds__(256) void scores_v2_kernel(
    const u16*   __restrict__ keysb,
    const u16*   __restrict__ W2T,
    const float* __restrict__ qp,
    const float* __restrict__ v,
    float*       __restrict__ part)
{
    __shared__ __align__(16) u16 Alds[BM * BK];
    __shared__ __align__(16) u16 Blds[BN * BK];

    const int tid  = threadIdx.x;
    const int nt   = blockIdx.x;            // 8
    const int n0   = nt * BN;
    const int m0   = blockIdx.y * BM;       // 256
    const int wave = tid >> 6, lane = tid & 63;
    const int wr = wave >> 1, wc = wave & 1;
    const int quad = lane >> 4, c16 = lane & 15;

    // per-thread staging coords: idx = i*256 + tid; r = idx>>3, c = idx&7
    const int sr = tid >> 3;                // row 0..31 (+32 per i)
    const int sc = tid & 7;                 // chunk 0..7

    f32x4 acc[4][4];
    #pragma unroll
    for (int i = 0; i < 4; ++i)
        #pragma unroll
        for (int j = 0; j < 4; ++j)
            acc[i][j] = f32x4{0.f, 0.f, 0.f, 0.f};

    for (int kt = 0; kt < HIDDEN; kt += BK) {
        __syncthreads();
        // A: 128 rows x 8 chunks of 16B; 4 issues/thread
        #pragma unroll
        for (int i = 0; i < 4; ++i) {
            int r = sr + i * 32;
            int csw = sc ^ (r & 7);
            const u16* src = keysb + (size_t)(m0 + r) * HIDDEN + kt + csw * 8;
            las_ptr dst = (las_ptr)((char*)Alds + (i * 256 + wave * 64) * 16);
            __builtin_amdgcn_global_load_lds((gas_ptr)src, dst, 16, 0, 0);
        }
        // B: same for W2T rows n0..n0+127
        #pragma unroll
        for (int i = 0; i < 4; ++i) {
            int r = sr + i * 32;
            int csw = sc ^ (r & 7);
            const u16* src = W2T + (size_t)(n0 + r) * HIDDEN + kt + csw * 8;
            las_ptr dst = (las_ptr)((char*)Blds + (i * 256 + wave * 64) * 16);
            __builtin_amdgcn_global_load_lds((gas_ptr)src, dst, 16, 0, 0);
        }
        __syncthreads();

        #pragma unroll
        for (int ks = 0; ks < BK; ks += 32) {
            const int ch = (ks >> 3) + quad;          // 16B chunk in row
            bf16x8 af[4], bfr[4];
            #pragma unroll
            for (int i = 0; i < 4; ++i) {
                int row = wr * 64 + i * 16 + c16;
                af[i] = __builtin_bit_cast(bf16x8,
                    *(const u16x8*)&Alds[row * BK + ((ch ^ (row & 7)) << 3)]);
            }
            #pragma unroll
            for (int j = 0; j < 4; ++j) {
                int row = wc * 64 + j * 16 + c16;
                bfr[j] = __builtin_bit_cast(bf16x8,
                    *(const u16x8*)&Blds[row * BK + ((ch ^ (row & 7)) << 3)]);
            }
            #pragma unroll
            for (int i = 0; i < 4; ++i)
                #pragma unroll
                for (int j = 0; j < 4; ++j)
                    acc[i][j] = __builtin_amdgcn_mfma_f32_16x16x32_bf16(
                        af[i], bfr[j], acc[i][j], 0, 0, 0);
        }
    }

    const int b = m0 >> 11;
    float qv[4], vv[4];
    #pragma unroll
    for (int j = 0; j < 4; ++j) {
        int n = n0 + wc * 64 + j * 16 + c16;
        qv[j] = qp[b * HIDDEN + n];
        vv[j] = v[n];
    }
    const int slot = nt * 2 + wc;
    #pragma unroll
    for (int i = 0; i < 4; ++i) {
        #pragma unroll
        for (int r = 0; r < 4; ++r) {
            float s = 0.f;
            #pragma unroll
            for (int j = 0; j < 4; ++j)
                s += fast_tanh(acc[i][j][r] + qv[j]) * vv[j];
            s += __shfl_xor(s, 1);
            s += __shfl_xor(s, 2);
            s += __shfl_xor(s, 4);
            s += __shfl_xor(s, 8);
            if (c16 == 0) {
                int m = m0 + wr * 64 + i * 16 + quad * 4 + r;
                part[(size_t)slot * M_TOTAL + m] = s;
            }
        }
    }
}

// ---------------------------------------------------------------------------
// scores v1 (fallback if ws too small): inline fp32->bf16 convert staging
// ---------------------------------------------------------------------------
#define LDA 72

__global__ __launch_bounds__(256) void scores_v1_kernel(
    const float* __restrict__ keys,
    const u16*   __restrict__ W2T,
    const float* __restrict__ qp,
    const float* __restrict__ v,
    float*       __restrict__ part)
{
    __shared__ __align__(16) u16 Alds[BM][LDA];
    __shared__ __align__(16) u16 Blds[BN][LDA];

    const int tid  = threadIdx.x;
    const int nt   = blockIdx.x;
    const int n0   = nt * BN;
    const int m0   = blockIdx.y * BM;
    const int wave = tid >> 6, lane = tid & 63;
    const int wr = wave >> 1, wc = wave & 1;
    const int quad = lane >> 4, c16 = lane & 15;

    f32x4 acc[4][4];
    #pragma unroll
    for (int i = 0; i < 4; ++i)
        #pragma unroll
        for (int j = 0; j < 4; ++j)
            acc[i][j] = f32x4{0.f, 0.f, 0.f, 0.f};

    for (int kt = 0; kt < HIDDEN; kt += BK) {
        __syncthreads();
        const float* gA = keys + (size_t)m0 * HIDDEN + kt;
        #pragma unroll
        for (int i = 0; i < 8; ++i) {
            int idx = tid + i * 256;
            int r = idx >> 4, c4 = idx & 15;
            float4 f = *(const float4*)(gA + (size_t)r * HIDDEN + c4 * 4);
            u16x4 pk;
            pk[0] = f2bf(f.x); pk[1] = f2bf(f.y);
            pk[2] = f2bf(f.z); pk[3] = f2bf(f.w);
            *(u16x4*)&Alds[r][c4 * 4] = pk;
        }
        #pragma unroll
        for (int i = 0; i < 4; ++i) {
            int idx = tid + i * 256;
            int r = idx >> 3, c8 = idx & 7;
            uint4 raw = ((const uint4*)(W2T + (size_t)(n0 + r) * HIDDEN + kt))[c8];
            *(uint4*)&Blds[r][c8 * 8] = raw;
        }
        __syncthreads();

        #pragma unroll
        for (int ks = 0; ks < BK; ks += 32) {
            bf16x8 af[4], bfr[4];
            #pragma unroll
            for (int i = 0; i < 4; ++i)
                af[i] = __builtin_bit_cast(bf16x8,
                    *(const u16x8*)&Alds[wr * 64 + i * 16 + c16][ks + quad * 8]);
            #pragma unroll
            for (int j = 0; j < 4; ++j)
                bfr[j] = __builtin_bit_cast(bf16x8,
                    *(const u16x8*)&Blds[wc * 64 + j * 16 + c16][ks + quad * 8]);
            #pragma unroll
            for (int i = 0; i < 4; ++i)
                #pragma unroll
                for (int j = 0; j < 4; ++j)
                    acc[i][j] = __builtin_amdgcn_mfma_f32_16x16x32_bf16(
                        af[i], bfr[j], acc[i][j], 0, 0, 0);
        }
    }

    const int b = m0 >> 11;
    float qv[4], vv[4];
    #pragma unroll
    for (int j = 0; j < 4; ++j) {
        int n = n0 + wc * 64 + j * 16 + c16;
        qv[j] = qp[b * HIDDEN + n];
        vv[j] = v[n];
    }
    const int slot = nt * 2 + wc;
    #pragma unroll
    for (int i = 0; i < 4; ++i) {
        #pragma unroll
        for (int r = 0; r < 4; ++r) {
            float s = 0.f;
            #pragma unroll
            for (int j = 0; j < 4; ++j)
                s += fast_tanh(acc[i][j][r] + qv[j]) * vv[j];
            s += __shfl_xor(s, 1);
            s += __shfl_xor(s, 2);
            s += __shfl_xor(s, 4);
            s += __shfl_xor(s, 8);
            if (c16 == 0) {
                int m = m0 + wr * 64 + i * 16 + quad * 4 + r;
                part[(size_t)slot * M_TOTAL + m] = s;
            }
        }
    }
}

// ---------------------------------------------------------------------------
// softmax: sum 16 part slots -> mask -> softmax. 1024 thr, 2 s each.
// ---------------------------------------------------------------------------
__global__ __launch_bounds__(1024) void softmax_kernel(
    const float* __restrict__ part, const int* __restrict__ mask,
    float* __restrict__ attn)
{
    const int b = blockIdx.x, tid = threadIdx.x;
    const int wave = tid >> 6, lane = tid & 63;
    __shared__ float red[16];
    float sc[2];
    float mx = -1e30f;
    #pragma unroll
    for (int j = 0; j < 2; ++j) {
        int s = tid + j * 1024;
        float a = 0.f;
        #pragma unroll
        for (int p = 0; p < 16; ++p)
            a += part[(size_t)p * M_TOTAL + b * SEQ + s];
        if (mask[b * SEQ + s] == 0) a = NEG_INF;
        sc[j] = a;
        mx = fmaxf(mx, a);
    }
    #pragma unroll
    for (int o = 32; o > 0; o >>= 1) mx = fmaxf(mx, __shfl_xor(mx, o));
    if (lane == 0) red[wave] = mx;
    __syncthreads();
    #pragma unroll
    for (int w = 0; w < 16; ++w) mx = fmaxf(mx, red[w]);
    float sum = 0.f;
    #pragma unroll
    for (int j = 0; j < 2; ++j) { sc[j] = __expf(sc[j] - mx); sum += sc[j]; }
    #pragma unroll
    for (int o = 32; o > 0; o >>= 1) sum += __shfl_xor(sum, o);
    __syncthreads();
    if (lane == 0) red[wave] = sum;
    __syncthreads();
    sum = 0.f;
    #pragma unroll
    for (int w = 0; w < 16; ++w) sum += red[w];
    float inv = 1.0f / sum;
    #pragma unroll
    for (int j = 0; j < 2; ++j)
        attn[b * SEQ + tid + j * 1024] = sc[j] * inv;
}

// ---------------------------------------------------------------------------
// context stage 1: ctxp[b*64+sch][h] = sum_{s in 32-chunk} attn*values
// grid (16 b, 64 sch) = 1024 blocks (4/CU)
// ---------------------------------------------------------------------------
__global__ __launch_bounds__(256) void ctx_part_kernel(
    const float* __restrict__ values, const float* __restrict__ attn,
    float* __restrict__ ctxp)
{
    const int b = blockIdx.x, sch = blockIdx.y, tid = threadIdx.x;
    __shared__ float w[32];
    if (tid < 32) w[tid] = attn[b * SEQ + sch * 32 + tid];
    __syncthreads();
    float4 acc = {0.f, 0.f, 0.f, 0.f};
    const float4* V = (const float4*)(values
        + (size_t)b * SEQ * HIDDEN + (size_t)sch * 32 * HIDDEN);
    #pragma unroll 4
    for (int s = 0; s < 32; ++s) {
        float wv = w[s];
        if (wv != 0.0f) {
            float4 x = V[(size_t)s * (HIDDEN / 4) + tid];
            acc.x += wv * x.x; acc.y += wv * x.y;
            acc.z += wv * x.z; acc.w += wv * x.w;
        }
    }
    ((float4*)(ctxp + (size_t)(b * 64 + sch) * HIDDEN))[tid] = acc;
}

// context stage 2: ctx[b][h] = sum_sch ctxp[b*64+sch][h]
__global__ __launch_bounds__(256) void ctx_reduce_kernel(
    const float* __restrict__ ctxp, float* __restrict__ ctx)
{
    const int b = blockIdx.x, tid = threadIdx.x;
    float4 acc = {0.f, 0.f, 0.f, 0.f};
    const float4* P = (const float4*)(ctxp + (size_t)b * 64 * HIDDEN);
    #pragma unroll 8
    for (int s = 0; s < 64; ++s) {
        float4 x = P[(size_t)s * (HIDDEN / 4) + tid];
        acc.x += x.x; acc.y += x.y; acc.z += x.z; acc.w += x.w;
    }
    ((float4*)(ctx + (size_t)b * HIDDEN))[tid] = acc;
}

// ---------------------------------------------------------------------------
extern "C" void kernel_launch(void* const* d_in, const int* in_sizes, int n_in,
                              void* d_out, int out_size, void* d_ws, size_t ws_size,
                              hipStream_t stream)
{
    const float* query  = (const float*)d_in[0];
    const float* keys   = (const float*)d_in[1];
    const float* values = (const float*)d_in[2];
    const int*   mask   = (const int*)d_in[3];
    const float* W1     = (const float*)d_in[4];
    const float* W2     = (const float*)d_in[5];
    const float* v      = (const float*)d_in[6];
    float* out = (float*)d_out;

    // ws layout:
    //   qp      64 KiB
    //   W2T      2 MiB  (bf16 [n][k])
    //   part     2 MiB  (16 x 32768 f32)
    //   ctxp     4 MiB  (1024 x 1024 f32)     [big path]
    //   keys_bf 64 MiB  (bf16 [32768][1024])  [big path]
    char* ws = (char*)d_ws;
    float* qp     = (float*)ws;
    u16*   w2t    = (u16*)(ws + (64 << 10));
    float* part   = (float*)(ws + (64 << 10) + (2 << 20));
    float* ctxp   = (float*)(ws + (64 << 10) + (4 << 20));
    u16*   keysb  = (u16*)(ws + (64 << 10) + (8 << 20));
    const size_t WS_BIG = (64 << 10) + (8 << 20) + ((size_t)64 << 20);

    float* attn_out = out + BATCH * HIDDEN;

    qproj_kernel<<<dim3(16, 16), 256, 0, stream>>>(query, W1, qp);
    w2t_kernel  <<<dim3(16, 16), 256, 0, stream>>>(W2, w2t);

    if (ws_size >= WS_BIG) {
        // 8388608 float4 total / 256 per block = 32768 blocks (was 16384:
        // only converted half of keys -> batches 8..15 got poison. R2 bug.)
        conv_kernel<<<32768, 256, 0, stream>>>(keys, keysb);
        scores_v2_kernel<<<dim3(8, 256), 256, 0, stream>>>(
            keysb, w2t, qp, v, part);
        softmax_kernel<<<16, 1024, 0, stream>>>(part, mask, attn_out);
        ctx_part_kernel<<<dim3(16, 64), 256, 0, stream>>>(
            values, attn_out, ctxp);
        ctx_reduce_kernel<<<16, 256, 0, stream>>>(ctxp, out);
    } else {
        scores_v1_kernel<<<dim3(8, 256), 256, 0, stream>>>(
            keys, w2t, qp, v, part);
        softmax_kernel<<<16, 1024, 0, stream>>>(part, mask, attn_out);
        if (ws_size >= (64 << 10) + (8 << 20)) {
            ctx_part_kernel<<<dim3(16, 64), 256, 0, stream>>>(
                values, attn_out, ctxp);
            ctx_reduce_kernel<<<16, 256, 0, stream>>>(ctxp, out);
        } else {
            hipMemsetAsync(d_out, 0, BATCH * HIDDEN * sizeof(float), stream);
            ctx_part_kernel<<<dim3(16, 64), 256, 0, stream>>>(
                values, attn_out, (float*)d_ws);
            ctx_reduce_kernel<<<16, 256, 0, stream>>>((float*)d_ws, out);
        }
    }
}